// Round 7
// baseline (47.214 us; speedup 1.0000x reference)
//
#include <hip/hip_runtime.h>
#include <stdint.h>

// Problem constants
static constexpr int NB = 16;     // batch
static constexpr int CI = 32;     // in channels
static constexpr int CO = 64;     // out channels
static constexpr int HI = 224, WI = 224;
static constexpr int HO = 112, WO = 112;
static constexpr int HW = HI * WI;
static constexpr float EPS = 1e-5f;

typedef _Float16 h2 __attribute__((ext_vector_type(2)));
typedef _Float16 h8 __attribute__((ext_vector_type(8)));
typedef float f32x4 __attribute__((ext_vector_type(4)));

__device__ __forceinline__ uint32_t pack_h2(float a, float b) {
    union { uint32_t u; h2 h; } c;
    c.h = (h2){(_Float16)a, (_Float16)b};
    return c.u;
}

// Workspace layout (bytes): packed weights only.
static constexpr size_t OFF_WT2 = 3072;   // wbits: CO*12 u32 = 3072
static constexpr size_t OFF_A1  = 7168;   // wt2:   16*CO u32 = 4096
static constexpr size_t OFF_CC  = 7424;   // A1/Cc: CO f32 each
static constexpr size_t WS_NEED = 7680;

// Padded s_xb column index: breaks stride-32B bank conflicts, keeps even-col
// 8B alignment for b64 reads.
__device__ __forceinline__ int XB(int c) { return c + ((c >> 3) << 2); }
static constexpr int XBW = 132 + ((132 / 8) << 2) + 4;   // 200 u32 per row

__global__ __launch_bounds__(256) void prep_kernel(
    const float* __restrict__ wbody,
    const float* __restrict__ g1, const float* __restrict__ b1,
    const float* __restrict__ m1, const float* __restrict__ v1,
    const float* __restrict__ wds,
    const float* __restrict__ g2, const float* __restrict__ b2,
    const float* __restrict__ m2, const float* __restrict__ v2,
    uint32_t* __restrict__ wbits, uint32_t* __restrict__ wt2,
    float* __restrict__ A1, float* __restrict__ Cc)
{
    int i = blockIdx.x * 256 + threadIdx.x;
    if (i < 16 * CO) {
        int ci2 = i >> 6, co = i & 63;
        float inv2 = g2[co] * rsqrtf(v2[co] + EPS);
        float w0 = wds[co * CI + 2 * ci2]     * inv2;
        float w1 = wds[co * CI + 2 * ci2 + 1] * inv2;
        wt2[i] = pack_h2(w0, w1);
    } else if (i < 16 * CO + CO * 9) {
        int j = i - 16 * CO;
        int co = j / 9, k = j % 9;
        uint32_t bits = 0u;
#pragma unroll
        for (int ci = 0; ci < CI; ++ci) {
            float wv = wbody[(co * CI + ci) * 9 + k];
            bits |= (uint32_t)(wv >= 0.0f) << ci;
        }
        wbits[co * 12 + k] = bits;
    } else if (i < 16 * CO + CO * 9 + CO) {
        int co = i - 16 * CO - CO * 9;
        float inv1 = g1[co] * rsqrtf(v1[co] + EPS);
        float inv2 = g2[co] * rsqrtf(v2[co] + EPS);
        A1[co] = -2.0f * inv1;
        Cc[co] = b1[co] - m1[co] * inv1 + b2[co] - m2[co] * inv2 + 288.0f * inv1;
    }
}

// Fused kernel, 1-output-row blocks: (b, oh, 64-wide ow tile), 128 threads,
// grid = 16*112*2 = 3584 -> ~14 blocks/CU with a real dispatch queue so block
// phases stagger (derive of queued blocks overlaps compute of resident ones).
// Derive uses the proven pack_kernel quad mapping (both input rows local to a
// thread); compute = R6's MFMA downsample + D-layout popc body, ct-loop over
// the wave's two co-tiles.
__global__ __launch_bounds__(128) void fused_kernel(
    const float* __restrict__ x,
    const uint32_t* __restrict__ wbits, const uint32_t* __restrict__ wt2,
    const float* __restrict__ A1p, const float* __restrict__ Ccp,
    float* __restrict__ out)
{
    // XCD-chunked bijective swizzle: 3584 = 8 * 448; consecutive bids share rows.
    const int bid  = (blockIdx.x & 7) * 448 + (blockIdx.x >> 3);
    const int tile = bid & 1;
    const int rest = bid >> 1;         // 0..1791
    const int oh   = rest % HO;
    const int b    = rest / HO;
    const int ow0  = tile * 64;
    const int t    = threadIdx.x;      // 0..127

    // LDS: 2400 + 4352 + 4096 + 3072 + 512 = 14,432 B
    __shared__ __align__(16) uint32_t s_xb[3][XBW];   // input rows 2oh-1..2oh+1
    __shared__ __align__(16) uint32_t s_avg[16][68];  // avgpool row oh (ci2 x ow)
    __shared__ __align__(16) uint32_t s_wt2[16][64];
    __shared__ __align__(16) uint32_t s_wb[CO * 12];
    __shared__ float s_A1[CO], s_C[CO];

    // ---- Burst 0: weight loads (oldest in vmcnt FIFO) ----
    uint32_t wtv[8], wbv[6];
    float a1v = 0.f, ccv = 0.f;
#pragma unroll
    for (int i = 0; i < 8; ++i) wtv[i] = wt2[t + 128 * i];
#pragma unroll
    for (int i = 0; i < 6; ++i) wbv[i] = wbits[t + 128 * i];
    if (t < CO) { a1v = A1p[t]; ccv = Ccp[t]; }

    // derive mapping (pack_kernel quad pattern): q = ci quarter, pp = col group
    const int q    = t & 3;          // ci 8q..8q+7
    const int pp   = t >> 2;         // 0..31: input cols 2ow0+4pp..+3
    const int jcol = 2 * ow0 + 4 * pp;
    const bool colok = (jcol + 3 < WI);

    // ---- Burst 1: 16 main float4 (2 input rows x 8 ci x 4 cols) ----
    const float* xp = x + ((size_t)(b * CI + 8 * q) * HI + 2 * oh) * WI + jcol;
    float4 L[16];
#pragma unroll
    for (int i = 0; i < 16; ++i) L[i] = make_float4(0.f, 0.f, 0.f, 0.f);
    if (colok) {
#pragma unroll
        for (int k = 0; k < 4; ++k) {
            L[4 * k + 0] = *(const float4*)(xp + (size_t)(2 * k) * HW);          // row0 ci even
            L[4 * k + 1] = *(const float4*)(xp + (size_t)(2 * k) * HW + WI);     // row1 ci even
            L[4 * k + 2] = *(const float4*)(xp + (size_t)(2 * k + 1) * HW);      // row0 ci odd
            L[4 * k + 3] = *(const float4*)(xp + (size_t)(2 * k + 1) * HW + WI); // row1 ci odd
        }
    }

    // ---- Burst 2: 8 halo-row float4 (row 2oh-1, all 8 ci of quarter) ----
    float4 H[8];
#pragma unroll
    for (int i = 0; i < 8; ++i) H[i] = make_float4(0.f, 0.f, 0.f, 0.f);
    if (oh > 0 && colok) {
        const float* xh = x + ((size_t)(b * CI + 8 * q) * HI + (2 * oh - 1)) * WI + jcol;
#pragma unroll
        for (int k = 0; k < 8; ++k)
            H[k] = *(const float4*)(xh + (size_t)k * HW);
    }

    // ---- Burst 3: halo-col scalars (threads 0..23: 3 rows x 8 ch-groups) ----
    const int wc = 2 * ow0 - 1;
    float hv[4] = {-1.f, -1.f, -1.f, -1.f};
    const int lr = t >> 3, lch = t & 7;
    const int hr = 2 * oh - 1 + lr;
    if (t < 24 && hr >= 0 && wc >= 0) {
        const float* xc = x + ((size_t)(b * CI + 4 * lch) * HI + hr) * WI + wc;
#pragma unroll
        for (int ci = 0; ci < 4; ++ci) hv[ci] = xc[(size_t)ci * HW];
    }

    // ---- Store weights to LDS ----
    {
        uint32_t* wt2s = (uint32_t*)s_wt2;
#pragma unroll
        for (int i = 0; i < 8; ++i) wt2s[t + 128 * i] = wtv[i];
#pragma unroll
        for (int i = 0; i < 6; ++i) s_wb[t + 128 * i] = wbv[i];
        if (t < CO) { s_A1[t] = a1v; s_C[t] = ccv; }
    }

    // ---- Process main rows (bits + avgpool) ----
    {
        uint32_t m0[4] = {0, 0, 0, 0}, m1r[4] = {0, 0, 0, 0};
#pragma unroll
        for (int k = 0; k < 4; ++k) {
            const float4 t0 = L[4 * k + 0], u0 = L[4 * k + 1];
            const float4 t1 = L[4 * k + 2], u1 = L[4 * k + 3];
            const int s0 = 8 * q + 2 * k, s1 = s0 + 1;
            m0[0]  |= ((uint32_t)(t0.x >= 0.f) << s0) | ((uint32_t)(t1.x >= 0.f) << s1);
            m0[1]  |= ((uint32_t)(t0.y >= 0.f) << s0) | ((uint32_t)(t1.y >= 0.f) << s1);
            m0[2]  |= ((uint32_t)(t0.z >= 0.f) << s0) | ((uint32_t)(t1.z >= 0.f) << s1);
            m0[3]  |= ((uint32_t)(t0.w >= 0.f) << s0) | ((uint32_t)(t1.w >= 0.f) << s1);
            m1r[0] |= ((uint32_t)(u0.x >= 0.f) << s0) | ((uint32_t)(u1.x >= 0.f) << s1);
            m1r[1] |= ((uint32_t)(u0.y >= 0.f) << s0) | ((uint32_t)(u1.y >= 0.f) << s1);
            m1r[2] |= ((uint32_t)(u0.z >= 0.f) << s0) | ((uint32_t)(u1.z >= 0.f) << s1);
            m1r[3] |= ((uint32_t)(u0.w >= 0.f) << s0) | ((uint32_t)(u1.w >= 0.f) << s1);
            // avgpool for ci2 = 4q+k at out-cols ow0+2pp, ow0+2pp+1
            float a0p0 = 0.25f * ((t0.x + t0.y) + (u0.x + u0.y));
            float a0p1 = 0.25f * ((t0.z + t0.w) + (u0.z + u0.w));
            float a1p0 = 0.25f * ((t1.x + t1.y) + (u1.x + u1.y));
            float a1p1 = 0.25f * ((t1.z + t1.w) + (u1.z + u1.w));
            *(uint2*)&s_avg[4 * q + k][2 * pp] =
                make_uint2(pack_h2(a0p0, a1p0), pack_h2(a0p1, a1p1));
        }
#pragma unroll
        for (int j = 0; j < 4; ++j) {
            m0[j]  |= __shfl_xor(m0[j], 1);  m0[j]  |= __shfl_xor(m0[j], 2);
            m1r[j] |= __shfl_xor(m1r[j], 1); m1r[j] |= __shfl_xor(m1r[j], 2);
        }
        uint32_t v0  = (q == 0) ? m0[0]  : (q == 1) ? m0[1]  : (q == 2) ? m0[2]  : m0[3];
        uint32_t v1v = (q == 0) ? m1r[0] : (q == 1) ? m1r[1] : (q == 2) ? m1r[2] : m1r[3];
        s_xb[1][XB(1 + 4 * pp + q)] = v0;
        s_xb[2][XB(1 + 4 * pp + q)] = v1v;
    }

    // ---- Process halo row ----
    {
        uint32_t mm[4] = {0, 0, 0, 0};
#pragma unroll
        for (int k = 0; k < 4; ++k) {
            const float4 t0 = H[2 * k], t1 = H[2 * k + 1];
            const int s0 = 8 * q + 2 * k, s1 = s0 + 1;
            mm[0] |= ((uint32_t)(t0.x >= 0.f) << s0) | ((uint32_t)(t1.x >= 0.f) << s1);
            mm[1] |= ((uint32_t)(t0.y >= 0.f) << s0) | ((uint32_t)(t1.y >= 0.f) << s1);
            mm[2] |= ((uint32_t)(t0.z >= 0.f) << s0) | ((uint32_t)(t1.z >= 0.f) << s1);
            mm[3] |= ((uint32_t)(t0.w >= 0.f) << s0) | ((uint32_t)(t1.w >= 0.f) << s1);
        }
        if (!(oh > 0 && colok)) { mm[0] = mm[1] = mm[2] = mm[3] = 0u; }
#pragma unroll
        for (int j = 0; j < 4; ++j) { mm[j] |= __shfl_xor(mm[j], 1); mm[j] |= __shfl_xor(mm[j], 2); }
        s_xb[0][XB(1 + 4 * pp + q)] = (q == 0) ? mm[0] : (q == 1) ? mm[1] : (q == 2) ? mm[2] : mm[3];
    }
    // ---- Process halo column (threads 0..23) ----
    if (t < 24) {
        uint32_t bits = 0u;
        if (hr >= 0 && wc >= 0) {
#pragma unroll
            for (int ci = 0; ci < 4; ++ci)
                bits |= (uint32_t)(hv[ci] >= 0.0f) << (4 * lch + ci);
        }
        bits |= __shfl_xor(bits, 1);
        bits |= __shfl_xor(bits, 2);
        bits |= __shfl_xor(bits, 4);
        if (lch == 0) s_xb[lr][XB(0)] = bits;
    }
    __syncthreads();

    // ---------------- Phase 2: MFMA downsample + D-layout popc body ----------
    const int w   = t >> 6;          // wave id: co 32w..32w+31
    const int l15 = t & 15;          // D col = pixel within tile; A col = co
    const int lk  = (t >> 4) & 3;    // k-slice group; D row group

    const int npt = (tile == 0) ? 4 : 3;   // tile1 pixel-tile 3 is fully OOB
    const bool ohf = (oh == 0);

    union U8 { uint32_t u[4]; h8 h; };

#pragma unroll 1
    for (int ct = 0; ct < 2; ++ct) {
        const int cb16 = 32 * w + 16 * ct;   // co tile base

        // A fragment: A[m=co=cb16+l15][k=8lk+2i..+1] = s_wt2[4lk+i][cb16+l15]
        U8 af;
#pragma unroll
        for (int i = 0; i < 4; ++i) af.u[i] = s_wt2[4 * lk + i][cb16 + l15];

        // body weights + BN constants for co_j = cb16 + 4lk + j
        uint32_t wv[4][9];
        float n2a[4], ccs[4];
#pragma unroll
        for (int j = 0; j < 4; ++j) {
            const int co = cb16 + 4 * lk + j;
            uint4 wa  = *(const uint4*)&s_wb[co * 12];
            uint4 wb4 = *(const uint4*)&s_wb[co * 12 + 4];
            wv[j][0] = wa.x;  wv[j][1] = wa.y;  wv[j][2] = wa.z;  wv[j][3] = wa.w;
            wv[j][4] = wb4.x; wv[j][5] = wb4.y; wv[j][6] = wb4.z; wv[j][7] = wb4.w;
            wv[j][8] = s_wb[co * 12 + 8];
            n2a[j] = s_A1[co]; ccs[j] = s_C[co];
        }

#pragma unroll 1
        for (int pt = 0; pt < npt; ++pt) {
            // B fragment: B[k=8lk+2i..+1][n=pix=16pt+l15]
            U8 bf;
#pragma unroll
            for (int i = 0; i < 4; ++i) bf.u[i] = s_avg[4 * lk + i][16 * pt + l15];
            f32x4 acc = {0.f, 0.f, 0.f, 0.f};
            acc = __builtin_amdgcn_mfma_f32_16x16x32_f16(af.h, bf.h, acc, 0, 0, 0);

            // body taps for pixel p_rel = 16pt + l15: s_xb cols c0..c0+2
            const int c0 = 32 * pt + 2 * l15;
            const int i0 = XB(c0);
            const int i2 = XB(c0 + 2);
            uint32_t xr[3][3];
#pragma unroll
            for (int rI = 0; rI < 3; ++rI) {
                const uint32_t* row = s_xb[rI];
                uint2 v = *(const uint2*)&row[i0];
                xr[rI][0] = v.x; xr[rI][1] = v.y; xr[rI][2] = row[i2];
            }

            const bool pleft = (tile == 0 && pt == 0 && l15 == 0);
            float res[4];
#pragma unroll
            for (int j = 0; j < 4; ++j) {
                int c00 = __popc(xr[0][0] ^ wv[j][0]);
                int c01 = __popc(xr[0][1] ^ wv[j][1]);
                int c02 = __popc(xr[0][2] ^ wv[j][2]);
                int c10 = __popc(xr[1][0] ^ wv[j][3]);
                int c11 = __popc(xr[1][1] ^ wv[j][4]);
                int c12 = __popc(xr[1][2] ^ wv[j][5]);
                int c20 = __popc(xr[2][0] ^ wv[j][6]);
                int c21 = __popc(xr[2][1] ^ wv[j][7]);
                int c22 = __popc(xr[2][2] ^ wv[j][8]);
                int r0v  = c00 + c01 + c02;
                int ssum = r0v + c10 + c11 + c12 + c20 + c21 + c22;
                if (ohf) ssum += 48 - r0v;               // top image row
                if (pleft) {                             // left image column
                    ssum += 48 - (c00 + c10 + c20);
                    if (ohf) ssum += c00 - 16;           // corner double-fix
                }
                res[j] = fmaf(n2a[j], (float)ssum, acc[j] + ccs[j]);
            }
            const size_t pbase = (size_t)ow0 + 16 * pt + l15;
#pragma unroll
            for (int j = 0; j < 4; ++j) {
                const int co = cb16 + 4 * lk + j;
                out[((size_t)(b * CO + co) * HO + oh) * WO + pbase] = res[j];
            }
        }
    }
}

// Fallback if workspace is too small: direct per-output computation (slow, correct).
__global__ __launch_bounds__(256) void naive_kernel(
    const float* __restrict__ x, const float* __restrict__ wbody,
    const float* __restrict__ g1, const float* __restrict__ b1,
    const float* __restrict__ m1, const float* __restrict__ v1,
    const float* __restrict__ wds,
    const float* __restrict__ g2, const float* __restrict__ b2,
    const float* __restrict__ m2, const float* __restrict__ v2,
    float* __restrict__ out)
{
    int i = blockIdx.x * 256 + threadIdx.x;
    if (i >= NB * CO * HO * WO) return;
    int ow = i % WO;
    int oh = (i / WO) % HO;
    int co = (i / (WO * HO)) % CO;
    int b  = i / (WO * HO * CO);
    float inv1 = g1[co] * rsqrtf(v1[co] + EPS);
    float inv2 = g2[co] * rsqrtf(v2[co] + EPS);
    int body = 0;
    float ds = 0.f;
    for (int ci = 0; ci < CI; ++ci) {
        const float* xp = x + (size_t)(b * CI + ci) * HW;
        for (int kh = 0; kh < 3; ++kh) {
            int hh = 2 * oh - 1 + kh;
            if (hh < 0 || hh >= HI) continue;
            for (int kw = 0; kw < 3; ++kw) {
                int ww = 2 * ow - 1 + kw;
                if (ww < 0 || ww >= WI) continue;
                float xv = xp[(size_t)hh * WI + ww];
                float wv = wbody[((co * CI + ci) * 3 + kh) * 3 + kw];
                int sx = (xv >= 0.f) ? 1 : -1;
                int sw = (wv >= 0.f) ? 1 : -1;
                body += sx * sw;
            }
        }
        float a = 0.25f * (xp[(size_t)(2 * oh) * WI + 2 * ow]
                         + xp[(size_t)(2 * oh) * WI + 2 * ow + 1]
                         + xp[(size_t)(2 * oh + 1) * WI + 2 * ow]
                         + xp[(size_t)(2 * oh + 1) * WI + 2 * ow + 1]);
        ds += a * wds[co * CI + ci];
    }
    out[i] = inv1 * (float)body + (b1[co] - m1[co] * inv1)
           + inv2 * ds + (b2[co] - m2[co] * inv2);
}

extern "C" void kernel_launch(void* const* d_in, const int* in_sizes, int n_in,
                              void* d_out, int out_size, void* d_ws, size_t ws_size,
                              hipStream_t stream)
{
    (void)in_sizes; (void)n_in; (void)out_size;
    const float* x   = (const float*)d_in[0];
    const float* wbd = (const float*)d_in[1];
    const float* g1  = (const float*)d_in[2];
    const float* b1  = (const float*)d_in[3];
    const float* m1  = (const float*)d_in[4];
    const float* v1  = (const float*)d_in[5];
    const float* wds = (const float*)d_in[6];
    const float* g2  = (const float*)d_in[7];
    const float* b2  = (const float*)d_in[8];
    const float* m2  = (const float*)d_in[9];
    const float* v2  = (const float*)d_in[10];
    float* out = (float*)d_out;

    if (ws_size < WS_NEED) {
        int total = NB * CO * HO * WO;
        naive_kernel<<<(total + 255) / 256, 256, 0, stream>>>(
            x, wbd, g1, b1, m1, v1, wds, g2, b2, m2, v2, out);
        return;
    }

    char* wsb = (char*)d_ws;
    uint32_t* wbits = (uint32_t*)wsb;
    uint32_t* wt2   = (uint32_t*)(wsb + OFF_WT2);
    float*    A1    = (float*)(wsb + OFF_A1);
    float*    Cc    = (float*)(wsb + OFF_CC);

    prep_kernel<<<7, 256, 0, stream>>>(wbd, g1, b1, m1, v1, wds, g2, b2, m2, v2,
                                       wbits, wt2, A1, Cc);
    // grid = NB * 112 rows * 2 ow tiles = 3584 blocks (= 8 * 448), 128 threads
    fused_kernel<<<dim3(NB * HO * 2), 128, 0, stream>>>(
        x, wbits, wt2, A1, Cc, out);
}

// Round 8
// 45.650 us; speedup vs baseline: 1.0343x; 1.0343x over previous
//
#include <hip/hip_runtime.h>
#include <stdint.h>

// Problem constants
static constexpr int NB = 16;     // batch
static constexpr int CI = 32;     // in channels
static constexpr int CO = 64;     // out channels
static constexpr int HI = 224, WI = 224;
static constexpr int HO = 112, WO = 112;
static constexpr int HW = HI * WI;
static constexpr float EPS = 1e-5f;

typedef _Float16 h2 __attribute__((ext_vector_type(2)));
typedef _Float16 h8 __attribute__((ext_vector_type(8)));
typedef float f32x4 __attribute__((ext_vector_type(4)));

__device__ __forceinline__ uint32_t pack_h2(float a, float b) {
    union { uint32_t u; h2 h; } c;
    c.h = (h2){(_Float16)a, (_Float16)b};
    return c.u;
}
// sign bit (1 if negative). x>=0 <=> sign==0 (randn: no NaN / -0.0 concern)
__device__ __forceinline__ uint32_t su(float x) { return __float_as_uint(x) >> 31; }

// Workspace layout (bytes): packed weights only.
static constexpr size_t OFF_WT2 = 3072;   // wbits: CO*12 u32 = 3072
static constexpr size_t OFF_A1  = 7168;   // wt2:   16*CO u32 = 4096
static constexpr size_t OFF_CC  = 7424;   // A1/Cc: CO f32 each
static constexpr size_t WS_NEED = 7680;

// Padded s_xb column index: breaks stride-32B bank conflicts, keeps even-col
// 8B alignment for b64 reads.
__device__ __forceinline__ int XB(int c) { return c + ((c >> 3) << 2); }
static constexpr int XBW = 132 + ((132 / 8) << 2) + 4;   // 200 u32 per row

__global__ __launch_bounds__(256) void prep_kernel(
    const float* __restrict__ wbody,
    const float* __restrict__ g1, const float* __restrict__ b1,
    const float* __restrict__ m1, const float* __restrict__ v1,
    const float* __restrict__ wds,
    const float* __restrict__ g2, const float* __restrict__ b2,
    const float* __restrict__ m2, const float* __restrict__ v2,
    uint32_t* __restrict__ wbits, uint32_t* __restrict__ wt2,
    float* __restrict__ A1, float* __restrict__ Cc)
{
    int i = blockIdx.x * 256 + threadIdx.x;
    if (i < 16 * CO) {
        int ci2 = i >> 6, co = i & 63;
        // 0.25 avgpool factor folded into the fp16 weight (exact exponent shift)
        float inv2 = 0.25f * g2[co] * rsqrtf(v2[co] + EPS);
        float w0 = wds[co * CI + 2 * ci2]     * inv2;
        float w1 = wds[co * CI + 2 * ci2 + 1] * inv2;
        wt2[i] = pack_h2(w0, w1);
    } else if (i < 16 * CO + CO * 9) {
        int j = i - 16 * CO;
        int co = j / 9, k = j % 9;
        uint32_t bits = 0u;
#pragma unroll
        for (int ci = 0; ci < CI; ++ci) {
            float wv = wbody[(co * CI + ci) * 9 + k];
            bits |= (uint32_t)(wv >= 0.0f) << ci;
        }
        wbits[co * 12 + k] = bits;
    } else if (i < 16 * CO + CO * 9 + CO) {
        int co = i - 16 * CO - CO * 9;
        float inv1 = g1[co] * rsqrtf(v1[co] + EPS);
        float inv2 = g2[co] * rsqrtf(v2[co] + EPS);
        A1[co] = -2.0f * inv1;
        Cc[co] = b1[co] - m1[co] * inv1 + b2[co] - m2[co] * inv2 + 288.0f * inv1;
    }
}

// Fused kernel, R6 structure (2 output rows / block, 1792 blocks, 256 thr)
// with the instruction diet:
//  - weights bypass LDS entirely: af/wv/n2a/ccs loaded global->reg in phase 2
//    (7.4 KB, L2-resident, 16-lane broadcast pattern) -> no staging instrs,
//    no s_wt2 4-way bank conflicts, LDS 20.4 -> 12.7 KB.
//  - sign-bit derive: bits accumulated from float sign bits (2 VALU/elem vs 3),
//    single NOT per stored word after the OR-butterfly.
//  - 0.25 avgpool factor folded into wt2 at prep (16 muls/thread saved).
__global__ __launch_bounds__(256) void fused_kernel(
    const float* __restrict__ x,
    const uint32_t* __restrict__ wbits, const uint32_t* __restrict__ wt2,
    const float* __restrict__ A1p, const float* __restrict__ Ccp,
    float* __restrict__ out)
{
    // XCD-chunked bijective swizzle: 1792 = 8 * 224.
    const int bid  = (blockIdx.x & 7) * 224 + (blockIdx.x >> 3);
    const int tile = bid & 1;
    const int gb   = bid >> 1;
    const int g    = gb % 56;          // row-pair group: output rows 2g, 2g+1
    const int b    = gb / 56;
    const int oh0  = 2 * g;
    const int ow0  = tile * 64;
    const int t    = threadIdx.x;

    // LDS: 4000 + 8704 = 12,704 B
    __shared__ __align__(16) uint32_t s_xb[5][XBW];     // rows rel -1..3, padded cols
    __shared__ __align__(16) uint32_t s_avg[2][16][68]; // [out-row r][ci2][local ow]

    // per-thread derive indexing
    const int pair = t >> 7;        // 0..1 -> input rows 2oh0+2pair, +1
    const int q    = t & 3;         // ci quarter (ci = 8q..8q+7)
    const int f    = (t >> 2) & 31; // float4 col group: in-cols 2ow0+4f..+3
    const int jcol = 2 * ow0 + 4 * f;
    const bool colok = (jcol + 3 < WI);

    // ---- Burst 1: 16 main-row float4 loads ----
    const float* xp = x + ((size_t)(b * CI + 8 * q) * HI + (oh0 * 2 + 2 * pair)) * WI + jcol;
    float4 L[16];
#pragma unroll
    for (int i = 0; i < 16; ++i) L[i] = make_float4(0.f, 0.f, 0.f, 0.f);
    if (colok) {
#pragma unroll
        for (int k = 0; k < 4; ++k) {
            L[4 * k + 0] = *(const float4*)(xp + (size_t)(2 * k) * HW);
            L[4 * k + 1] = *(const float4*)(xp + (size_t)(2 * k) * HW + WI);
            L[4 * k + 2] = *(const float4*)(xp + (size_t)(2 * k + 1) * HW);
            L[4 * k + 3] = *(const float4*)(xp + (size_t)(2 * k + 1) * HW + WI);
        }
    }

    // ---- Burst 2: 8 halo-row float4 loads (threads 0..127) ----
    float4 H[8];
#pragma unroll
    for (int i = 0; i < 8; ++i) H[i] = make_float4(0.f, 0.f, 0.f, 0.f);
    if (t < 128 && g > 0 && colok) {
        const float* xh = x + ((size_t)(b * CI + 8 * q) * HI + (oh0 * 2 - 1)) * WI + jcol;
#pragma unroll
        for (int k = 0; k < 8; ++k)
            H[k] = *(const float4*)(xh + (size_t)k * HW);
    }

    // ---- Burst 3: 4 halo-col scalar loads (threads 0..39) ----
    const int wc = 2 * ow0 - 1;
    float hv[4] = {-1.f, -1.f, -1.f, -1.f};
    const int lr = t >> 3, lch = t & 7;          // only meaningful for t<40
    const int hr = oh0 * 2 - 1 + lr;
    if (t < 40 && hr >= 0 && wc >= 0) {
        const float* xc = x + ((size_t)(b * CI + 4 * lch) * HI + hr) * WI + wc;
#pragma unroll
        for (int ci = 0; ci < 4; ++ci) hv[ci] = xc[(size_t)ci * HW];
    }

    // ---- Process main rows: sign-bit masks + avgpool (0.25 folded out) ----
    {
        uint32_t m0[4] = {0, 0, 0, 0}, m1r[4] = {0, 0, 0, 0};
#pragma unroll
        for (int k = 0; k < 4; ++k) {
            const float4 t0 = L[4 * k + 0], u0 = L[4 * k + 1];
            const float4 t1 = L[4 * k + 2], u1 = L[4 * k + 3];
            const int s0 = 8 * q + 2 * k, s1 = s0 + 1;
            m0[0]  += su(t0.x) << s0;  m0[0]  += su(t1.x) << s1;
            m0[1]  += su(t0.y) << s0;  m0[1]  += su(t1.y) << s1;
            m0[2]  += su(t0.z) << s0;  m0[2]  += su(t1.z) << s1;
            m0[3]  += su(t0.w) << s0;  m0[3]  += su(t1.w) << s1;
            m1r[0] += su(u0.x) << s0;  m1r[0] += su(u1.x) << s1;
            m1r[1] += su(u0.y) << s0;  m1r[1] += su(u1.y) << s1;
            m1r[2] += su(u0.z) << s0;  m1r[2] += su(u1.z) << s1;
            m1r[3] += su(u0.w) << s0;  m1r[3] += su(u1.w) << s1;
            float a0p0 = (t0.x + t0.y) + (u0.x + u0.y);
            float a0p1 = (t0.z + t0.w) + (u0.z + u0.w);
            float a1p0 = (t1.x + t1.y) + (u1.x + u1.y);
            float a1p1 = (t1.z + t1.w) + (u1.z + u1.w);
            *(uint2*)&s_avg[pair][4 * q + k][2 * f] =
                make_uint2(pack_h2(a0p0, a1p0), pack_h2(a0p1, a1p1));
        }
#pragma unroll
        for (int j = 0; j < 4; ++j) {
            m0[j]  |= __shfl_xor(m0[j], 1);  m0[j]  |= __shfl_xor(m0[j], 2);
            m1r[j] |= __shfl_xor(m1r[j], 1); m1r[j] |= __shfl_xor(m1r[j], 2);
        }
        // invert once per stored word: bit=1 <=> x>=0 (matches old semantics;
        // zero-filled OOB words become all-ones exactly as before -> unread)
        uint32_t v0  = ~((q == 0) ? m0[0]  : (q == 1) ? m0[1]  : (q == 2) ? m0[2]  : m0[3]);
        uint32_t v1v = ~((q == 0) ? m1r[0] : (q == 1) ? m1r[1] : (q == 2) ? m1r[2] : m1r[3]);
        s_xb[1 + 2 * pair][XB(1 + 4 * f + q)] = v0;
        s_xb[2 + 2 * pair][XB(1 + 4 * f + q)] = v1v;
    }

    // ---- Process halo row (threads 0..127) ----
    if (t < 128) {
        uint32_t mm[4] = {0, 0, 0, 0};
#pragma unroll
        for (int k = 0; k < 4; ++k) {
            const float4 t0 = H[2 * k], t1 = H[2 * k + 1];
            const int s0 = 8 * q + 2 * k, s1 = s0 + 1;
            mm[0] += su(t0.x) << s0;  mm[0] += su(t1.x) << s1;
            mm[1] += su(t0.y) << s0;  mm[1] += su(t1.y) << s1;
            mm[2] += su(t0.z) << s0;  mm[2] += su(t1.z) << s1;
            mm[3] += su(t0.w) << s0;  mm[3] += su(t1.w) << s1;
        }
#pragma unroll
        for (int j = 0; j < 4; ++j) { mm[j] |= __shfl_xor(mm[j], 1); mm[j] |= __shfl_xor(mm[j], 2); }
        uint32_t vh = ~((q == 0) ? mm[0] : (q == 1) ? mm[1] : (q == 2) ? mm[2] : mm[3]);
        // out-of-image rows/cols must store 0 (the ssum corrections assume it)
        if (!(g > 0 && colok)) vh = 0u;
        s_xb[0][XB(1 + 4 * f + q)] = vh;
    }
    // ---- Process halo column (threads 0..39) ----
    if (t < 40) {
        uint32_t bits = 0u;
#pragma unroll
        for (int ci = 0; ci < 4; ++ci)
            bits += su(hv[ci]) << (4 * lch + ci);   // hv=-1 for OOB -> sign 1 -> 0 after NOT
        bits |= __shfl_xor(bits, 1);
        bits |= __shfl_xor(bits, 2);
        bits |= __shfl_xor(bits, 4);
        if (lch == 0) s_xb[lr][XB(0)] = ~bits & 0xFFFFFFFFu;
    }
    __syncthreads();

    // ---------------- Phase 2: MFMA downsample + D-layout popc body ----------
    const int w   = t >> 6;          // wave id = co tile (co base 16w)
    const int l15 = t & 15;          // D col = pixel within tile; A col = co
    const int lk  = (t >> 4) & 3;    // k-slice group; D row group

    // Weights direct from global (L2-resident, broadcast across 16 lanes).
    union U8 { uint32_t u[4]; h8 h; };
    U8 af;
#pragma unroll
    for (int i = 0; i < 4; ++i) af.u[i] = wt2[(4 * lk + i) * 64 + 16 * w + l15];

    uint32_t wv[4][9];
    float n2a[4], ccs[4];
#pragma unroll
    for (int j = 0; j < 4; ++j) {
        const int co = 16 * w + 4 * lk + j;
        uint4 wa  = *(const uint4*)&wbits[co * 12];
        uint4 wb4 = *(const uint4*)&wbits[co * 12 + 4];
        wv[j][0] = wa.x;  wv[j][1] = wa.y;  wv[j][2] = wa.z;  wv[j][3] = wa.w;
        wv[j][4] = wb4.x; wv[j][5] = wb4.y; wv[j][6] = wb4.z; wv[j][7] = wb4.w;
        wv[j][8] = wbits[co * 12 + 8];
        n2a[j] = A1p[co]; ccs[j] = Ccp[co];
    }

    const int npt = (tile == 0) ? 4 : 3;   // tile1 pixel-tile 3 is fully OOB

#pragma unroll 1
    for (int r = 0; r < 2; ++r) {
        const bool ohf = (g == 0 && r == 0);
#pragma unroll 1
        for (int pt = 0; pt < npt; ++pt) {
            // B fragment: B[k=8lk+2i..+1][n=pix=16pt+l15]
            U8 bf;
#pragma unroll
            for (int i = 0; i < 4; ++i) bf.u[i] = s_avg[r][4 * lk + i][16 * pt + l15];
            f32x4 acc = {0.f, 0.f, 0.f, 0.f};
            acc = __builtin_amdgcn_mfma_f32_16x16x32_f16(af.h, bf.h, acc, 0, 0, 0);

            // body taps for pixel p_rel = 16pt + l15: s_xb cols c0..c0+2
            const int c0 = 32 * pt + 2 * l15;
            const int i0 = XB(c0);
            const int i2 = XB(c0 + 2);
            uint32_t xr[3][3];
#pragma unroll
            for (int rI = 0; rI < 3; ++rI) {
                const uint32_t* row = s_xb[2 * r + rI];
                uint2 v = *(const uint2*)&row[i0];
                xr[rI][0] = v.x; xr[rI][1] = v.y; xr[rI][2] = row[i2];
            }

            const bool pleft = (tile == 0 && pt == 0 && l15 == 0);
            float res[4];
#pragma unroll
            for (int j = 0; j < 4; ++j) {
                int c00 = __popc(xr[0][0] ^ wv[j][0]);
                int c01 = __popc(xr[0][1] ^ wv[j][1]);
                int c02 = __popc(xr[0][2] ^ wv[j][2]);
                int c10 = __popc(xr[1][0] ^ wv[j][3]);
                int c11 = __popc(xr[1][1] ^ wv[j][4]);
                int c12 = __popc(xr[1][2] ^ wv[j][5]);
                int c20 = __popc(xr[2][0] ^ wv[j][6]);
                int c21 = __popc(xr[2][1] ^ wv[j][7]);
                int c22 = __popc(xr[2][2] ^ wv[j][8]);
                int r0v  = c00 + c01 + c02;
                int ssum = r0v + c10 + c11 + c12 + c20 + c21 + c22;
                if (ohf) ssum += 48 - r0v;               // top image row
                if (pleft) {                             // left image column
                    ssum += 48 - (c00 + c10 + c20);
                    if (ohf) ssum += c00 - 16;           // corner double-fix
                }
                res[j] = fmaf(n2a[j], (float)ssum, acc[j] + ccs[j]);
            }
            // store: co rows 16w+4lk+j, pixel ow0+16pt+l15 (coalesced per l15 group)
            const size_t pbase = (size_t)ow0 + 16 * pt + l15;
#pragma unroll
            for (int j = 0; j < 4; ++j) {
                const int co = 16 * w + 4 * lk + j;
                out[((size_t)(b * CO + co) * HO + (oh0 + r)) * WO + pbase] = res[j];
            }
        }
    }
}

// Fallback if workspace is too small: direct per-output computation (slow, correct).
__global__ __launch_bounds__(256) void naive_kernel(
    const float* __restrict__ x, const float* __restrict__ wbody,
    const float* __restrict__ g1, const float* __restrict__ b1,
    const float* __restrict__ m1, const float* __restrict__ v1,
    const float* __restrict__ wds,
    const float* __restrict__ g2, const float* __restrict__ b2,
    const float* __restrict__ m2, const float* __restrict__ v2,
    float* __restrict__ out)
{
    int i = blockIdx.x * 256 + threadIdx.x;
    if (i >= NB * CO * HO * WO) return;
    int ow = i % WO;
    int oh = (i / WO) % HO;
    int co = (i / (WO * HO)) % CO;
    int b  = i / (WO * HO * CO);
    float inv1 = g1[co] * rsqrtf(v1[co] + EPS);
    float inv2 = g2[co] * rsqrtf(v2[co] + EPS);
    int body = 0;
    float ds = 0.f;
    for (int ci = 0; ci < CI; ++ci) {
        const float* xp = x + (size_t)(b * CI + ci) * HW;
        for (int kh = 0; kh < 3; ++kh) {
            int hh = 2 * oh - 1 + kh;
            if (hh < 0 || hh >= HI) continue;
            for (int kw = 0; kw < 3; ++kw) {
                int ww = 2 * ow - 1 + kw;
                if (ww < 0 || ww >= WI) continue;
                float xv = xp[(size_t)hh * WI + ww];
                float wv = wbody[((co * CI + ci) * 3 + kh) * 3 + kw];
                int sx = (xv >= 0.f) ? 1 : -1;
                int sw = (wv >= 0.f) ? 1 : -1;
                body += sx * sw;
            }
        }
        float a = 0.25f * (xp[(size_t)(2 * oh) * WI + 2 * ow]
                         + xp[(size_t)(2 * oh) * WI + 2 * ow + 1]
                         + xp[(size_t)(2 * oh + 1) * WI + 2 * ow]
                         + xp[(size_t)(2 * oh + 1) * WI + 2 * ow + 1]);
        ds += a * wds[co * CI + ci];
    }
    out[i] = inv1 * (float)body + (b1[co] - m1[co] * inv1)
           + inv2 * ds + (b2[co] - m2[co] * inv2);
}

extern "C" void kernel_launch(void* const* d_in, const int* in_sizes, int n_in,
                              void* d_out, int out_size, void* d_ws, size_t ws_size,
                              hipStream_t stream)
{
    (void)in_sizes; (void)n_in; (void)out_size;
    const float* x   = (const float*)d_in[0];
    const float* wbd = (const float*)d_in[1];
    const float* g1  = (const float*)d_in[2];
    const float* b1  = (const float*)d_in[3];
    const float* m1  = (const float*)d_in[4];
    const float* v1  = (const float*)d_in[5];
    const float* wds = (const float*)d_in[6];
    const float* g2  = (const float*)d_in[7];
    const float* b2  = (const float*)d_in[8];
    const float* m2  = (const float*)d_in[9];
    const float* v2  = (const float*)d_in[10];
    float* out = (float*)d_out;

    if (ws_size < WS_NEED) {
        int total = NB * CO * HO * WO;
        naive_kernel<<<(total + 255) / 256, 256, 0, stream>>>(
            x, wbd, g1, b1, m1, v1, wds, g2, b2, m2, v2, out);
        return;
    }

    char* wsb = (char*)d_ws;
    uint32_t* wbits = (uint32_t*)wsb;
    uint32_t* wt2   = (uint32_t*)(wsb + OFF_WT2);
    float*    A1    = (float*)(wsb + OFF_A1);
    float*    Cc    = (float*)(wsb + OFF_CC);

    prep_kernel<<<7, 256, 0, stream>>>(wbd, g1, b1, m1, v1, wds, g2, b2, m2, v2,
                                       wbits, wt2, A1, Cc);
    // grid = NB * 56 row-pair groups * 2 ow tiles = 1792 blocks (= 8 * 224)
    fused_kernel<<<dim3(NB * 56 * 2), 256, 0, stream>>>(
        x, wbits, wt2, A1, Cc, out);
}

// Round 9
// 44.883 us; speedup vs baseline: 1.0519x; 1.0171x over previous
//
#include <hip/hip_runtime.h>
#include <stdint.h>

// Problem constants
static constexpr int NB = 16;     // batch
static constexpr int CI = 32;     // in channels
static constexpr int CO = 64;     // out channels
static constexpr int HI = 224, WI = 224;
static constexpr int HO = 112, WO = 112;
static constexpr int HW = HI * WI;
static constexpr float EPS = 1e-5f;

typedef _Float16 h2 __attribute__((ext_vector_type(2)));
typedef _Float16 h8 __attribute__((ext_vector_type(8)));
typedef float f32x4 __attribute__((ext_vector_type(4)));

__device__ __forceinline__ uint32_t pack_h2(float a, float b) {
    union { uint32_t u; h2 h; } c;
    c.h = (h2){(_Float16)a, (_Float16)b};
    return c.u;
}
// sign bit (1 if negative). x>=0 <=> sign==0 (randn: no NaN / -0.0 concern)
__device__ __forceinline__ uint32_t su(float x) { return __float_as_uint(x) >> 31; }

// Workspace layout (bytes): packed weights only.
static constexpr size_t OFF_WT2 = 3072;   // wbits: CO*12 u32 = 3072
static constexpr size_t OFF_A1  = 7168;   // wt2:   16*CO u32 = 4096
static constexpr size_t OFF_CC  = 7424;   // A1/Cc: CO f32 each
static constexpr size_t WS_NEED = 7680;

// Padded s_xb column index: breaks stride-32B bank conflicts, keeps even-col
// 8B alignment for b64 reads.
__device__ __forceinline__ int XB(int c) { return c + ((c >> 3) << 2); }
static constexpr int XBW = 132 + ((132 / 8) << 2) + 4;   // 200 u32 per row

__global__ __launch_bounds__(256) void prep_kernel(
    const float* __restrict__ wbody,
    const float* __restrict__ g1, const float* __restrict__ b1,
    const float* __restrict__ m1, const float* __restrict__ v1,
    const float* __restrict__ wds,
    const float* __restrict__ g2, const float* __restrict__ b2,
    const float* __restrict__ m2, const float* __restrict__ v2,
    uint32_t* __restrict__ wbits, uint32_t* __restrict__ wt2,
    float* __restrict__ A1, float* __restrict__ Cc)
{
    int i = blockIdx.x * 256 + threadIdx.x;
    if (i < 16 * CO) {
        int ci2 = i >> 6, co = i & 63;
        // 0.25 avgpool factor folded into the fp16 weight (exact exponent shift)
        float inv2 = 0.25f * g2[co] * rsqrtf(v2[co] + EPS);
        float w0 = wds[co * CI + 2 * ci2]     * inv2;
        float w1 = wds[co * CI + 2 * ci2 + 1] * inv2;
        wt2[i] = pack_h2(w0, w1);
    } else if (i < 16 * CO + CO * 9) {
        int j = i - 16 * CO;
        int co = j / 9, k = j % 9;
        uint32_t bits = 0u;
#pragma unroll
        for (int ci = 0; ci < CI; ++ci) {
            float wv = wbody[(co * CI + ci) * 9 + k];
            bits |= (uint32_t)(wv >= 0.0f) << ci;
        }
        wbits[co * 12 + k] = bits;
    } else if (i < 16 * CO + CO * 9 + CO) {
        int co = i - 16 * CO - CO * 9;
        float inv1 = g1[co] * rsqrtf(v1[co] + EPS);
        float inv2 = g2[co] * rsqrtf(v2[co] + EPS);
        A1[co] = -2.0f * inv1;
        Cc[co] = b1[co] - m1[co] * inv1 + b2[co] - m2[co] * inv2 + 288.0f * inv1;
    }
}

// Fused kernel, R6 structure (2 output rows / block, 1792 blocks, 256 thr):
//  - burst-0 LDS weight staging restored (R8's global-per-wave weight reads
//    exposed L2 latency after the barrier and regressed);
//  - s_wt2 padded to stride 66: af read rows 4lk+i had row-stride 64 u32 ->
//    same bank across lk quarters (4-way conflict); 66 -> offsets 0/8/16/24;
//  - sign-bit derive + folded 0.25 kept from R8 (VALU cut, verified);
//  - s_setprio(1) around phase 2 (favor compute-phase waves on the CU).
__global__ __launch_bounds__(256) void fused_kernel(
    const float* __restrict__ x,
    const uint32_t* __restrict__ wbits, const uint32_t* __restrict__ wt2,
    const float* __restrict__ A1p, const float* __restrict__ Ccp,
    float* __restrict__ out)
{
    // XCD-chunked bijective swizzle: 1792 = 8 * 224.
    const int bid  = (blockIdx.x & 7) * 224 + (blockIdx.x >> 3);
    const int tile = bid & 1;
    const int gb   = bid >> 1;
    const int g    = gb % 56;          // row-pair group: output rows 2g, 2g+1
    const int b    = gb / 56;
    const int oh0  = 2 * g;
    const int ow0  = tile * 64;
    const int t    = threadIdx.x;

    // LDS: 4000 + 8704 + 4224 + 3072 + 512 = 20,512 B
    __shared__ __align__(16) uint32_t s_xb[5][XBW];     // rows rel -1..3, padded cols
    __shared__ __align__(16) uint32_t s_avg[2][16][68]; // [out-row r][ci2][local ow]
    __shared__ __align__(16) uint32_t s_wt2[16][66];    // stride 66: af conflict-free
    __shared__ __align__(16) uint32_t s_wb[CO * 12];
    __shared__ float s_A1[CO], s_C[CO];

    // ---- Burst 0: weight loads (oldest in vmcnt FIFO, complete first) ----
    uint32_t wtv[4], wbv[3];
    float a1v = 0.f, ccv = 0.f;
#pragma unroll
    for (int i = 0; i < 4; ++i) wtv[i] = wt2[t + 256 * i];
#pragma unroll
    for (int i = 0; i < 3; ++i) wbv[i] = wbits[t + 256 * i];
    if (t < CO) { a1v = A1p[t]; ccv = Ccp[t]; }

    // per-thread derive indexing
    const int pair = t >> 7;        // 0..1 -> input rows 2oh0+2pair, +1
    const int q    = t & 3;         // ci quarter (ci = 8q..8q+7)
    const int f    = (t >> 2) & 31; // float4 col group: in-cols 2ow0+4f..+3
    const int jcol = 2 * ow0 + 4 * f;
    const bool colok = (jcol + 3 < WI);

    // ---- Burst 1: 16 main-row float4 loads ----
    const float* xp = x + ((size_t)(b * CI + 8 * q) * HI + (oh0 * 2 + 2 * pair)) * WI + jcol;
    float4 L[16];
#pragma unroll
    for (int i = 0; i < 16; ++i) L[i] = make_float4(0.f, 0.f, 0.f, 0.f);
    if (colok) {
#pragma unroll
        for (int k = 0; k < 4; ++k) {
            L[4 * k + 0] = *(const float4*)(xp + (size_t)(2 * k) * HW);
            L[4 * k + 1] = *(const float4*)(xp + (size_t)(2 * k) * HW + WI);
            L[4 * k + 2] = *(const float4*)(xp + (size_t)(2 * k + 1) * HW);
            L[4 * k + 3] = *(const float4*)(xp + (size_t)(2 * k + 1) * HW + WI);
        }
    }

    // ---- Burst 2: 8 halo-row float4 loads (threads 0..127) ----
    float4 H[8];
#pragma unroll
    for (int i = 0; i < 8; ++i) H[i] = make_float4(0.f, 0.f, 0.f, 0.f);
    if (t < 128 && g > 0 && colok) {
        const float* xh = x + ((size_t)(b * CI + 8 * q) * HI + (oh0 * 2 - 1)) * WI + jcol;
#pragma unroll
        for (int k = 0; k < 8; ++k)
            H[k] = *(const float4*)(xh + (size_t)k * HW);
    }

    // ---- Burst 3: 4 halo-col scalar loads (threads 0..39) ----
    const int wc = 2 * ow0 - 1;
    float hv[4] = {-1.f, -1.f, -1.f, -1.f};
    const int lr = t >> 3, lch = t & 7;          // only meaningful for t<40
    const int hr = oh0 * 2 - 1 + lr;
    if (t < 40 && hr >= 0 && wc >= 0) {
        const float* xc = x + ((size_t)(b * CI + 4 * lch) * HI + hr) * WI + wc;
#pragma unroll
        for (int ci = 0; ci < 4; ++ci) hv[ci] = xc[(size_t)ci * HW];
    }

    // ---- Store weights to LDS (waits only on burst-0 FIFO entries) ----
    {
#pragma unroll
        for (int i = 0; i < 4; ++i) {
            const int idx = t + 256 * i;
            s_wt2[idx >> 6][idx & 63] = wtv[i];
        }
#pragma unroll
        for (int i = 0; i < 3; ++i) s_wb[t + 256 * i] = wbv[i];
        if (t < CO) { s_A1[t] = a1v; s_C[t] = ccv; }
    }

    // ---- Process main rows: sign-bit masks + avgpool (0.25 folded out) ----
    {
        uint32_t m0[4] = {0, 0, 0, 0}, m1r[4] = {0, 0, 0, 0};
#pragma unroll
        for (int k = 0; k < 4; ++k) {
            const float4 t0 = L[4 * k + 0], u0 = L[4 * k + 1];
            const float4 t1 = L[4 * k + 2], u1 = L[4 * k + 3];
            const int s0 = 8 * q + 2 * k, s1 = s0 + 1;
            m0[0]  += su(t0.x) << s0;  m0[0]  += su(t1.x) << s1;
            m0[1]  += su(t0.y) << s0;  m0[1]  += su(t1.y) << s1;
            m0[2]  += su(t0.z) << s0;  m0[2]  += su(t1.z) << s1;
            m0[3]  += su(t0.w) << s0;  m0[3]  += su(t1.w) << s1;
            m1r[0] += su(u0.x) << s0;  m1r[0] += su(u1.x) << s1;
            m1r[1] += su(u0.y) << s0;  m1r[1] += su(u1.y) << s1;
            m1r[2] += su(u0.z) << s0;  m1r[2] += su(u1.z) << s1;
            m1r[3] += su(u0.w) << s0;  m1r[3] += su(u1.w) << s1;
            float a0p0 = (t0.x + t0.y) + (u0.x + u0.y);
            float a0p1 = (t0.z + t0.w) + (u0.z + u0.w);
            float a1p0 = (t1.x + t1.y) + (u1.x + u1.y);
            float a1p1 = (t1.z + t1.w) + (u1.z + u1.w);
            *(uint2*)&s_avg[pair][4 * q + k][2 * f] =
                make_uint2(pack_h2(a0p0, a1p0), pack_h2(a0p1, a1p1));
        }
#pragma unroll
        for (int j = 0; j < 4; ++j) {
            m0[j]  |= __shfl_xor(m0[j], 1);  m0[j]  |= __shfl_xor(m0[j], 2);
            m1r[j] |= __shfl_xor(m1r[j], 1); m1r[j] |= __shfl_xor(m1r[j], 2);
        }
        // invert once per stored word: bit=1 <=> x>=0 (zero-filled OOB words
        // become all-ones exactly as before -> unread)
        uint32_t v0  = ~((q == 0) ? m0[0]  : (q == 1) ? m0[1]  : (q == 2) ? m0[2]  : m0[3]);
        uint32_t v1v = ~((q == 0) ? m1r[0] : (q == 1) ? m1r[1] : (q == 2) ? m1r[2] : m1r[3]);
        s_xb[1 + 2 * pair][XB(1 + 4 * f + q)] = v0;
        s_xb[2 + 2 * pair][XB(1 + 4 * f + q)] = v1v;
    }

    // ---- Process halo row (threads 0..127) ----
    if (t < 128) {
        uint32_t mm[4] = {0, 0, 0, 0};
#pragma unroll
        for (int k = 0; k < 4; ++k) {
            const float4 t0 = H[2 * k], t1 = H[2 * k + 1];
            const int s0 = 8 * q + 2 * k, s1 = s0 + 1;
            mm[0] += su(t0.x) << s0;  mm[0] += su(t1.x) << s1;
            mm[1] += su(t0.y) << s0;  mm[1] += su(t1.y) << s1;
            mm[2] += su(t0.z) << s0;  mm[2] += su(t1.z) << s1;
            mm[3] += su(t0.w) << s0;  mm[3] += su(t1.w) << s1;
        }
#pragma unroll
        for (int j = 0; j < 4; ++j) { mm[j] |= __shfl_xor(mm[j], 1); mm[j] |= __shfl_xor(mm[j], 2); }
        uint32_t vh = ~((q == 0) ? mm[0] : (q == 1) ? mm[1] : (q == 2) ? mm[2] : mm[3]);
        // out-of-image rows/cols must store 0 (the ssum corrections assume it)
        if (!(g > 0 && colok)) vh = 0u;
        s_xb[0][XB(1 + 4 * f + q)] = vh;
    }
    // ---- Process halo column (threads 0..39) ----
    if (t < 40) {
        uint32_t bits = 0u;
#pragma unroll
        for (int ci = 0; ci < 4; ++ci)
            bits += su(hv[ci]) << (4 * lch + ci);   // hv=-1 for OOB -> sign 1 -> 0 after NOT
        bits |= __shfl_xor(bits, 1);
        bits |= __shfl_xor(bits, 2);
        bits |= __shfl_xor(bits, 4);
        if (lch == 0) s_xb[lr][XB(0)] = ~bits & 0xFFFFFFFFu;
    }
    __syncthreads();

    // ---------------- Phase 2: MFMA downsample + D-layout popc body ----------
    const int w   = t >> 6;          // wave id = co tile (co base 16w)
    const int l15 = t & 15;          // D col = pixel within tile; A col = co
    const int lk  = (t >> 4) & 3;    // k-slice group; D row group

    __builtin_amdgcn_s_setprio(1);

    // A fragment (weights): A[m=co=16w+l15][k=8lk+2i..+1] = s_wt2[4lk+i][16w+l15]
    union U8 { uint32_t u[4]; h8 h; };
    U8 af;
#pragma unroll
    for (int i = 0; i < 4; ++i) af.u[i] = s_wt2[4 * lk + i][16 * w + l15];

    // body weights + BN constants for co_j = 16w + 4lk + j
    uint32_t wv[4][9];
    float n2a[4], ccs[4];
#pragma unroll
    for (int j = 0; j < 4; ++j) {
        const int co = 16 * w + 4 * lk + j;
        uint4 wa  = *(const uint4*)&s_wb[co * 12];
        uint4 wb4 = *(const uint4*)&s_wb[co * 12 + 4];
        wv[j][0] = wa.x;  wv[j][1] = wa.y;  wv[j][2] = wa.z;  wv[j][3] = wa.w;
        wv[j][4] = wb4.x; wv[j][5] = wb4.y; wv[j][6] = wb4.z; wv[j][7] = wb4.w;
        wv[j][8] = s_wb[co * 12 + 8];
        n2a[j] = s_A1[co]; ccs[j] = s_C[co];
    }

    const int npt = (tile == 0) ? 4 : 3;   // tile1 pixel-tile 3 is fully OOB

#pragma unroll 1
    for (int r = 0; r < 2; ++r) {
        const bool ohf = (g == 0 && r == 0);
#pragma unroll 1
        for (int pt = 0; pt < npt; ++pt) {
            // B fragment: B[k=8lk+2i..+1][n=pix=16pt+l15]
            U8 bf;
#pragma unroll
            for (int i = 0; i < 4; ++i) bf.u[i] = s_avg[r][4 * lk + i][16 * pt + l15];
            f32x4 acc = {0.f, 0.f, 0.f, 0.f};
            acc = __builtin_amdgcn_mfma_f32_16x16x32_f16(af.h, bf.h, acc, 0, 0, 0);

            // body taps for pixel p_rel = 16pt + l15: s_xb cols c0..c0+2
            const int c0 = 32 * pt + 2 * l15;
            const int i0 = XB(c0);
            const int i2 = XB(c0 + 2);
            uint32_t xr[3][3];
#pragma unroll
            for (int rI = 0; rI < 3; ++rI) {
                const uint32_t* row = s_xb[2 * r + rI];
                uint2 v = *(const uint2*)&row[i0];
                xr[rI][0] = v.x; xr[rI][1] = v.y; xr[rI][2] = row[i2];
            }

            const bool pleft = (tile == 0 && pt == 0 && l15 == 0);
            float res[4];
#pragma unroll
            for (int j = 0; j < 4; ++j) {
                int c00 = __popc(xr[0][0] ^ wv[j][0]);
                int c01 = __popc(xr[0][1] ^ wv[j][1]);
                int c02 = __popc(xr[0][2] ^ wv[j][2]);
                int c10 = __popc(xr[1][0] ^ wv[j][3]);
                int c11 = __popc(xr[1][1] ^ wv[j][4]);
                int c12 = __popc(xr[1][2] ^ wv[j][5]);
                int c20 = __popc(xr[2][0] ^ wv[j][6]);
                int c21 = __popc(xr[2][1] ^ wv[j][7]);
                int c22 = __popc(xr[2][2] ^ wv[j][8]);
                int r0v  = c00 + c01 + c02;
                int ssum = r0v + c10 + c11 + c12 + c20 + c21 + c22;
                if (ohf) ssum += 48 - r0v;               // top image row
                if (pleft) {                             // left image column
                    ssum += 48 - (c00 + c10 + c20);
                    if (ohf) ssum += c00 - 16;           // corner double-fix
                }
                res[j] = fmaf(n2a[j], (float)ssum, acc[j] + ccs[j]);
            }
            // store: co rows 16w+4lk+j, pixel ow0+16pt+l15 (coalesced per l15 group)
            const size_t pbase = (size_t)ow0 + 16 * pt + l15;
#pragma unroll
            for (int j = 0; j < 4; ++j) {
                const int co = 16 * w + 4 * lk + j;
                out[((size_t)(b * CO + co) * HO + (oh0 + r)) * WO + pbase] = res[j];
            }
        }
    }
    __builtin_amdgcn_s_setprio(0);
}

// Fallback if workspace is too small: direct per-output computation (slow, correct).
__global__ __launch_bounds__(256) void naive_kernel(
    const float* __restrict__ x, const float* __restrict__ wbody,
    const float* __restrict__ g1, const float* __restrict__ b1,
    const float* __restrict__ m1, const float* __restrict__ v1,
    const float* __restrict__ wds,
    const float* __restrict__ g2, const float* __restrict__ b2,
    const float* __restrict__ m2, const float* __restrict__ v2,
    float* __restrict__ out)
{
    int i = blockIdx.x * 256 + threadIdx.x;
    if (i >= NB * CO * HO * WO) return;
    int ow = i % WO;
    int oh = (i / WO) % HO;
    int co = (i / (WO * HO)) % CO;
    int b  = i / (WO * HO * CO);
    float inv1 = g1[co] * rsqrtf(v1[co] + EPS);
    float inv2 = g2[co] * rsqrtf(v2[co] + EPS);
    int body = 0;
    float ds = 0.f;
    for (int ci = 0; ci < CI; ++ci) {
        const float* xp = x + (size_t)(b * CI + ci) * HW;
        for (int kh = 0; kh < 3; ++kh) {
            int hh = 2 * oh - 1 + kh;
            if (hh < 0 || hh >= HI) continue;
            for (int kw = 0; kw < 3; ++kw) {
                int ww = 2 * ow - 1 + kw;
                if (ww < 0 || ww >= WI) continue;
                float xv = xp[(size_t)hh * WI + ww];
                float wv = wbody[((co * CI + ci) * 3 + kh) * 3 + kw];
                int sx = (xv >= 0.f) ? 1 : -1;
                int sw = (wv >= 0.f) ? 1 : -1;
                body += sx * sw;
            }
        }
        float a = 0.25f * (xp[(size_t)(2 * oh) * WI + 2 * ow]
                         + xp[(size_t)(2 * oh) * WI + 2 * ow + 1]
                         + xp[(size_t)(2 * oh + 1) * WI + 2 * ow]
                         + xp[(size_t)(2 * oh + 1) * WI + 2 * ow + 1]);
        ds += a * wds[co * CI + ci];
    }
    out[i] = inv1 * (float)body + (b1[co] - m1[co] * inv1)
           + inv2 * ds + (b2[co] - m2[co] * inv2);
}

extern "C" void kernel_launch(void* const* d_in, const int* in_sizes, int n_in,
                              void* d_out, int out_size, void* d_ws, size_t ws_size,
                              hipStream_t stream)
{
    (void)in_sizes; (void)n_in; (void)out_size;
    const float* x   = (const float*)d_in[0];
    const float* wbd = (const float*)d_in[1];
    const float* g1  = (const float*)d_in[2];
    const float* b1  = (const float*)d_in[3];
    const float* m1  = (const float*)d_in[4];
    const float* v1  = (const float*)d_in[5];
    const float* wds = (const float*)d_in[6];
    const float* g2  = (const float*)d_in[7];
    const float* b2  = (const float*)d_in[8];
    const float* m2  = (const float*)d_in[9];
    const float* v2  = (const float*)d_in[10];
    float* out = (float*)d_out;

    if (ws_size < WS_NEED) {
        int total = NB * CO * HO * WO;
        naive_kernel<<<(total + 255) / 256, 256, 0, stream>>>(
            x, wbd, g1, b1, m1, v1, wds, g2, b2, m2, v2, out);
        return;
    }

    char* wsb = (char*)d_ws;
    uint32_t* wbits = (uint32_t*)wsb;
    uint32_t* wt2   = (uint32_t*)(wsb + OFF_WT2);
    float*    A1    = (float*)(wsb + OFF_A1);
    float*    Cc    = (float*)(wsb + OFF_CC);

    prep_kernel<<<7, 256, 0, stream>>>(wbd, g1, b1, m1, v1, wds, g2, b2, m2, v2,
                                       wbits, wt2, A1, Cc);
    // grid = NB * 56 row-pair groups * 2 ow tiles = 1792 blocks (= 8 * 224)
    fused_kernel<<<dim3(NB * 56 * 2), 256, 0, stream>>>(
        x, wbits, wt2, A1, Cc, out);
}